// Round 2
// baseline (639.331 us; speedup 1.0000x reference)
//
#include <hip/hip_runtime.h>

#define BB 32
#define TT 512
#define KK 48
#define KK2 2304          // 48*48
#define START_TAG 46
#define STOP_TAG 47
#define L2E 1.4426950408889634f
#define LN2 0.6931471805599453f
#define NBUF 8            // LDS ring slots (power of 2)
#define DEPTH 5           // prefetch distance in steps

__device__ inline float fast_exp2(float x) {
#if __has_builtin(__builtin_amdgcn_exp2f)
  return __builtin_amdgcn_exp2f(x);
#else
  return exp2f(x);
#endif
}
__device__ inline float fast_log2(float x) {
#if __has_builtin(__builtin_amdgcn_logf)
  return __builtin_amdgcn_logf(x);
#else
  return log2f(x);
#endif
}

// One block per batch element. 192 threads = 3 waves.
// wave w owns columns [16w, 16w+16); lane l -> (j0 = l>>2, ig = l&3).
// Thread (j0, ig) reduces rows i = r*4 + ig (r = 0..11) for column j = 16w + j0.
// Features: LDS ring fring[NBUF][3 waves][48 rows][16 cols], staged with
// global_load_lds (3x dwordx4 per wave per step), depth-5 pipeline with
// counted vmcnt + raw s_barrier (never drain vmcnt(0) in the loop).
// Carry: log2-domain, double-buffered, PERMUTED layout carry_g[buf][(i&3)*12 + (i>>2)]
// so each thread's 12 carries are contiguous (3x ds_read_b128, conflict-free).
__global__ __launch_bounds__(192, 1) void crf_kernel(
    const float* __restrict__ feat,
    const int* __restrict__ targets,
    const int* __restrict__ lengths,
    float* __restrict__ ws,      // ws[0]=float accum, ws[1]=int counter (zeroed by memset)
    float* __restrict__ out) {

  __shared__ float fring[NBUF * KK2];   // 73728 B
  __shared__ float carry_g[2][KK];
  __shared__ float red[4];

  const int b   = blockIdx.x;
  const int len = lengths[b];
  const int tid = threadIdx.x;
  const int w   = tid >> 6;      // wave 0..2
  const int l   = tid & 63;      // lane
  const int j0  = l >> 2;        // 0..15
  const int ig  = l & 3;         // 0..3
  const int j   = w * 16 + j0;   // global column 0..47
  const float* fb = feat + (size_t)b * TT * KK2;

  // ---------- gold partial for this block (scattered gathers, one-time) ----------
  float gsum = 0.f;
  for (int t = tid; t < TT; t += 192) {
    if (t < len) gsum += fb[(size_t)t * KK2 + targets[b * TT + t]];
  }
  #pragma unroll
  for (int m = 1; m < 64; m <<= 1) gsum += __shfl_xor(gsum, m, 64);
  if (l == 0) red[w] = gsum;

  // ---------- carry init: carry[i] = feat[b,0,START,i] * log2(e), permuted ----------
  if (tid < KK) {
    float v = fb[START_TAG * KK + tid] * L2E;
    carry_g[0][(tid & 3) * 12 + (tid >> 2)] = v;
  }
  __syncthreads();   // pre-loop full barrier (vmcnt(0) drain here is one-time, fine)
  const float gold_b = red[0] + red[1] + red[2];

  // ---------- staging: wave w loads its 48x16 column panel for step t_src ----------
  auto stage = [&](int t_src, int slot) {
    const float* srcbase = fb + (size_t)t_src * KK2;
    #pragma unroll
    for (int q = 0; q < 3; ++q) {
      // lane l: global = rows q*16 + j0, cols w*16 + ig*4 .. +4  (16B, 64B-coalesced)
      const float* g = srcbase + (q * 16 + j0) * KK + w * 16 + ig * 4;
      // LDS dest: wave-uniform base; HW writes lane l at base + l*16B
      float* d = &fring[slot * KK2 + w * 768 + q * 256];
      __builtin_amdgcn_global_load_lds(
          (const __attribute__((address_space(1))) unsigned int*)(const void*)g,
          (__attribute__((address_space(3))) unsigned int*)(void*)d,
          16, 0, 0);
    }
  };

  // ---------- prologue: issue stages for t = 1..DEPTH ----------
  #pragma unroll
  for (int d = 0; d < DEPTH; ++d) {
    int ts = 1 + d;
    if (ts > len - 1) ts = (len > 1) ? (len - 1) : 0;  // clamp; garbage slots never read
    stage(ts, d);
  }
  // need stage(1) done: 4 newer stages (12 loads) may remain in flight
  asm volatile("s_waitcnt vmcnt(12) lgkmcnt(0)" ::: "memory");
  __builtin_amdgcn_s_barrier();
  asm volatile("" ::: "memory");

  // ---------- main scan loop: 1 raw barrier per step, vmcnt never drained ----------
  for (int t = 1; t < len; ++t) {
    const int slot = (t - 1) & (NBUF - 1);
    const int rd = (t - 1) & 1, wr = t & 1;
    const float* fr = &fring[slot * KK2 + w * 768];

    // carry slice: rows i = r*4+ig live at carry_g[rd][ig*12 + r] (contiguous)
    float c[12];
    #pragma unroll
    for (int q = 0; q < 3; ++q) {
      float4 cv = *reinterpret_cast<const float4*>(&carry_g[rd][ig * 12 + q * 4]);
      c[q * 4 + 0] = cv.x; c[q * 4 + 1] = cv.y;
      c[q * 4 + 2] = cv.z; c[q * 4 + 3] = cv.w;
    }

    // x[r] = feat[t][r*4+ig][j] * log2e + carry  (LDS reads: 2-way bank alias = free)
    float x[12];
    #pragma unroll
    for (int r = 0; r < 12; ++r)
      x[r] = fmaf(fr[(r * 4 + ig) * 16 + j0], L2E, c[r]);

    // max over the thread's 12, then over the 4-lane ig group
    float m0 = fmaxf(fmaxf(x[0], x[1]), fmaxf(x[2], x[3]));
    float m1 = fmaxf(fmaxf(x[4], x[5]), fmaxf(x[6], x[7]));
    float m2 = fmaxf(fmaxf(x[8], x[9]), fmaxf(x[10], x[11]));
    float m = fmaxf(fmaxf(m0, m1), m2);
    m = fmaxf(m, __shfl_xor(m, 1));
    m = fmaxf(m, __shfl_xor(m, 2));

    // sum of 2^(x-m), 4 accumulators to break the dependence chain
    float s0 = 0.f, s1 = 0.f, s2 = 0.f, s3 = 0.f;
    #pragma unroll
    for (int r = 0; r < 12; r += 4) {
      s0 += fast_exp2(x[r + 0] - m);
      s1 += fast_exp2(x[r + 1] - m);
      s2 += fast_exp2(x[r + 2] - m);
      s3 += fast_exp2(x[r + 3] - m);
    }
    float s = (s0 + s1) + (s2 + s3);
    s += __shfl_xor(s, 1);
    s += __shfl_xor(s, 2);
    float cn = m + fast_log2(s);

    if (ig == 0) carry_g[wr][(j & 3) * 12 + (j >> 2)] = cn;

    // issue stage for t+DEPTH (clamped; always 3 loads to keep vmcnt arithmetic uniform)
    int tn = t + DEPTH; if (tn > len - 1) tn = len - 1;
    stage(tn, (t - 1 + DEPTH) & (NBUF - 1));

    // stage(t+1) must be done before next iteration reads its slot:
    // newer stages t+2..t+DEPTH = (DEPTH-1)*3 = 12 loads may stay in flight.
    asm volatile("s_waitcnt vmcnt(12) lgkmcnt(0)" ::: "memory");
    __builtin_amdgcn_s_barrier();
    asm volatile("" ::: "memory");
  }

  // ---------- epilogue: per-block value, atomic combine, last block finalizes ----------
  if (tid == 0) {
    const int rdf = (len - 1) & 1;
    // STOP index 47 -> permuted idx (47&3)*12 + (47>>2) = 47
    float v = carry_g[rdf][47] * LN2 - gold_b;
    atomicAdd(&ws[0], v);
    __threadfence();
    int done = atomicAdd((int*)&ws[1], 1);
    if (done == BB - 1) {
      float tot = atomicAdd(&ws[0], 0.0f);   // atomic read of final total
      out[0] = tot / (float)BB;
    }
  }
}

extern "C" void kernel_launch(void* const* d_in, const int* in_sizes, int n_in,
                              void* d_out, int out_size, void* d_ws, size_t ws_size,
                              hipStream_t stream) {
  const float* feat  = (const float*)d_in[0];
  const int* targets = (const int*)d_in[1];
  const int* lengths = (const int*)d_in[2];
  float* ws  = (float*)d_ws;
  float* out = (float*)d_out;

  hipMemsetAsync(d_ws, 0, 16, stream);   // zero accum + counter
  crf_kernel<<<BB, 192, 0, stream>>>(feat, targets, lengths, ws, out);
}

// Round 3
// 395.104 us; speedup vs baseline: 1.6181x; 1.6181x over previous
//
#include <hip/hip_runtime.h>

#define BB 32
#define TT 512
#define KK 48
#define KK2 2304          // 48*48
#define START_TAG 46
#define STOP_TAG 47
#define L2E 1.4426950408889634f
#define LN2 0.6931471805599453f
#define SLAB 7            // steps per LDS slab; 2 slabs * 7 * 9216B = 129 KB LDS

__device__ inline float fast_exp2(float x) {
#if __has_builtin(__builtin_amdgcn_exp2f)
  return __builtin_amdgcn_exp2f(x);
#else
  return exp2f(x);
#endif
}
__device__ inline float fast_log2(float x) {
#if __has_builtin(__builtin_amdgcn_logf)
  return __builtin_amdgcn_logf(x);
#else
  return log2f(x);
#endif
}

// quad_perm DPP: 0xB1 = lane xor 1, 0x4E = lane xor 2 (within each quad)
template <int CTRL>
__device__ inline float dppf(float v) {
  int i = __float_as_int(v);
  int r = __builtin_amdgcn_update_dpp(i, i, CTRL, 0xF, 0xF, false);
  return __int_as_float(r);
}

// One block per batch. 192 threads = 3 waves.
// wave w owns columns [16w,16w+16); lane l -> (j0=l>>2, ig=l&3).
// Thread (j0,ig) reduces rows i = r*4+ig (r=0..11) for column j=16w+j0; the
// 4-lane quad combines via DPP quad_perm (full-rate VALU, no LDS latency).
// Features: 2 LDS slabs of SLAB steps each, staged via global_load_lds
// (21 loads/wave/slab issued at slab start), ONE vmcnt(0) per slab boundary.
// Per-step sync: ds_write carry -> s_waitcnt lgkmcnt(0) -> raw s_barrier.
// Carry: log2-domain, double-buffered, permuted layout carry_g[buf][(i&3)*12+(i>>2)]
// so each thread's 12 carries are one contiguous 48B run (3x ds_read_b128, broadcast).
__global__ __launch_bounds__(192, 1) void crf_kernel(
    const float* __restrict__ feat,
    const int* __restrict__ targets,
    const int* __restrict__ lengths,
    float* __restrict__ ws,      // ws[0]=float accum, ws[1]=int counter (memset 0)
    float* __restrict__ out) {

  __shared__ float fbuf[2][SLAB * KK2];   // 129024 B
  __shared__ float carry_g[2][KK];
  __shared__ float red[4];

  const int b   = blockIdx.x;
  const int len = lengths[b];
  const int tid = threadIdx.x;
  const int w   = tid >> 6;
  const int l   = tid & 63;
  const int j0  = l >> 2;
  const int ig  = l & 3;
  const int j   = w * 16 + j0;
  const float* fb = feat + (size_t)b * TT * KK2;

  // ---------- gold partial (one-time scattered gathers) ----------
  float gsum = 0.f;
  for (int t = tid; t < TT; t += 192)
    if (t < len) gsum += fb[(size_t)t * KK2 + targets[b * TT + t]];
  #pragma unroll
  for (int m = 1; m < 64; m <<= 1) gsum += __shfl_xor(gsum, m, 64);
  if (l == 0) red[w] = gsum;

  // ---------- carry init (log2 domain, permuted) ----------
  if (tid < KK)
    carry_g[0][(tid & 3) * 12 + (tid >> 2)] = fb[START_TAG * KK + tid] * L2E;

  const int nsteps = len - 1;
  const int nslab  = (nsteps + SLAB - 1) / SLAB;

  // wave w stages its 48x16 column panel for all SLAB steps of slab s
  auto stage_slab = [&](int s, int buf) {
    #pragma unroll
    for (int u = 0; u < SLAB; ++u) {
      int t = s * SLAB + 1 + u;
      if (t > len - 1) t = len - 1;   // clamp: in-bounds, data unused past len
      #pragma unroll
      for (int q = 0; q < 3; ++q) {
        const float* gq = fb + (size_t)t * KK2 + (q * 16 + j0) * KK + w * 16 + ig * 4;
        float* d = &fbuf[buf][u * KK2 + w * 768 + q * 256];
        __builtin_amdgcn_global_load_lds(
            (const __attribute__((address_space(1))) unsigned int*)(const void*)gq,
            (__attribute__((address_space(3))) unsigned int*)(void*)d,
            16, 0, 0);
      }
    }
  };

  if (nsteps > 0) stage_slab(0, 0);
  __syncthreads();   // one-time full drain: slab0 DMA + carry init + red
  const float gold_b = red[0] + red[1] + red[2];

  for (int s = 0; s < nslab; ++s) {
    const int buf = s & 1;
    if (s + 1 < nslab) stage_slab(s + 1, buf ^ 1);   // async into other slab
    const int base = s * SLAB + 1;
    const float* fs = &fbuf[buf][w * 768];

    // features for step u=0 of this slab (slab is ready: boundary barrier passed)
    float x[2][12];
    #pragma unroll
    for (int r = 0; r < 12; ++r) x[0][r] = fs[(r * 4 + ig) * 16 + j0];

    #pragma unroll
    for (int u = 0; u < SLAB; ++u) {
      const int t = base + u;
      if (t < len) {                         // block-uniform guard
        const int rd = (t - 1) & 1, wr = t & 1;

        // carry slice: thread's 12 rows contiguous at carry_g[rd][ig*12..]
        float c[12];
        #pragma unroll
        for (int q = 0; q < 3; ++q) {
          float4 cv = *reinterpret_cast<const float4*>(&carry_g[rd][ig * 12 + q * 4]);
          c[q * 4 + 0] = cv.x; c[q * 4 + 1] = cv.y;
          c[q * 4 + 2] = cv.z; c[q * 4 + 3] = cv.w;
        }

        float xv[12];
        #pragma unroll
        for (int r = 0; r < 12; ++r) xv[r] = fmaf(x[u & 1][r], L2E, c[r]);

        // prefetch next step's features (slab data is stable -> safe early)
        if (u + 1 < SLAB) {
          #pragma unroll
          for (int r = 0; r < 12; ++r)
            x[(u + 1) & 1][r] = fs[(u + 1) * KK2 + (r * 4 + ig) * 16 + j0];
        }

        // max over 12, then over the quad via DPP
        float m0 = fmaxf(fmaxf(xv[0], xv[1]), fmaxf(xv[2], xv[3]));
        float m1 = fmaxf(fmaxf(xv[4], xv[5]), fmaxf(xv[6], xv[7]));
        float m2 = fmaxf(fmaxf(xv[8], xv[9]), fmaxf(xv[10], xv[11]));
        float m = fmaxf(fmaxf(m0, m1), m2);
        m = fmaxf(m, dppf<0xB1>(m));
        m = fmaxf(m, dppf<0x4E>(m));

        // sum of 2^(x-m), 4 accumulators
        float s0 = 0.f, s1 = 0.f, s2 = 0.f, s3 = 0.f;
        #pragma unroll
        for (int r = 0; r < 12; r += 4) {
          s0 += fast_exp2(xv[r + 0] - m);
          s1 += fast_exp2(xv[r + 1] - m);
          s2 += fast_exp2(xv[r + 2] - m);
          s3 += fast_exp2(xv[r + 3] - m);
        }
        float sm = (s0 + s1) + (s2 + s3);
        sm += dppf<0xB1>(sm);
        sm += dppf<0x4E>(sm);
        float cn = m + fast_log2(sm);

        if (ig == 0) carry_g[wr][(j & 3) * 12 + (j >> 2)] = cn;

        // per-step: carry write only. Slab's last step: also drain next-slab DMA.
        if (u == SLAB - 1) {
          asm volatile("s_waitcnt vmcnt(0) lgkmcnt(0)" ::: "memory");
        } else {
          asm volatile("s_waitcnt lgkmcnt(0)" ::: "memory");
        }
        __builtin_amdgcn_s_barrier();
      }
    }
  }

  // ---------- epilogue ----------
  if (tid == 0) {
    const int rdf = (len - 1) & 1;    // len==1 -> 0 -> init buffer
    // STOP=47 -> permuted idx (47&3)*12 + (47>>2) = 47
    float v = carry_g[rdf][47] * LN2 - gold_b;
    atomicAdd(&ws[0], v);
    __threadfence();
    int done = atomicAdd((int*)&ws[1], 1);
    if (done == BB - 1) out[0] = atomicAdd(&ws[0], 0.0f) / (float)BB;
  }
}

extern "C" void kernel_launch(void* const* d_in, const int* in_sizes, int n_in,
                              void* d_out, int out_size, void* d_ws, size_t ws_size,
                              hipStream_t stream) {
  const float* feat  = (const float*)d_in[0];
  const int* targets = (const int*)d_in[1];
  const int* lengths = (const int*)d_in[2];
  float* ws  = (float*)d_ws;
  float* out = (float*)d_out;

  hipMemsetAsync(d_ws, 0, 16, stream);   // zero accum + counter
  crf_kernel<<<BB, 192, 0, stream>>>(feat, targets, lengths, ws, out);
}

// Round 4
// 389.742 us; speedup vs baseline: 1.6404x; 1.0138x over previous
//
#include <hip/hip_runtime.h>

#define BB 32
#define TT 512
#define KK 48
#define KK2 2304          // 48*48
#define START_TAG 46
#define STOP_TAG 47
#define L2E 1.4426950408889634f
#define LN2 0.6931471805599453f

typedef int v4i __attribute__((ext_vector_type(4)));

__device__ inline float fast_exp2(float x) {
#if __has_builtin(__builtin_amdgcn_exp2f)
  return __builtin_amdgcn_exp2f(x);
#else
  return exp2f(x);
#endif
}
__device__ inline float fast_log2(float x) {
#if __has_builtin(__builtin_amdgcn_logf)
  return __builtin_amdgcn_logf(x);
#else
  return log2f(x);
#endif
}

// quad_perm DPP: 0xB1 = swap lane^1, 0x4E = swap lane^2 (within each quad)
template <int CTRL>
__device__ inline float dppf(float v) {
  int i = __float_as_int(v);
  int r = __builtin_amdgcn_update_dpp(i, i, CTRL, 0xF, 0xF, false);
  return __int_as_float(r);
}

// One block per batch. 192 threads = 3 waves.
// lane l: j0 = l>>2 (0..15), ig = l&3; column j = w*16+j0; rows = ig*12 + r.
// Features: global -> VGPR via inline-asm buffer_load_dword (un-sinkable,
// no LDS-DMA, no compiler vmcnt interference). 4-slot register ring
// (prefetch depth 4 steps), per-step counted s_waitcnt vmcnt(36).
// Carry: log2-domain, natural layout, double-buffered in LDS; per step
// 3x broadcast ds_read_b128 + 1 ds_write + lgkmcnt(0) + raw s_barrier.
// LSE shift: previous step's quad-max (deferred shift) -> max tree off the
// recurrence critical path. exp2 args bounded (~|feat spread|+log2 K), safe.

// ---- 12 buffer loads for one ring slot; offsets r*192 fit imm12 ----
#define BL(dst, OFFLIT)                                                      \
  asm volatile("buffer_load_dword %0, %1, %2, 0 offen offset:" OFFLIT        \
               : "=v"(dst) : "v"(voff), "s"(rsrc))
#define LOAD12(P) do {                                                       \
  BL(P##0, "0");    BL(P##1, "192");  BL(P##2, "384");  BL(P##3, "576");     \
  BL(P##4, "768");  BL(P##5, "960");  BL(P##6, "1152"); BL(P##7, "1344");    \
  BL(P##8, "1536"); BL(P##9, "1728"); BL(P##10, "1920"); BL(P##11, "2112");  \
  voff += (unsigned)(KK2 * 4);                                               \
} while (0)

#define STEP(P, TCUR) do {                                                   \
  const int _rd = ((TCUR) - 1) & 1, _wr = (TCUR) & 1;                        \
  float4 _c0 = *(const float4*)&carry_g[_rd][ig * 12 + 0];                   \
  float4 _c1 = *(const float4*)&carry_g[_rd][ig * 12 + 4];                   \
  float4 _c2 = *(const float4*)&carry_g[_rd][ig * 12 + 8];                   \
  asm volatile("s_waitcnt vmcnt(36)" ::: "memory");                          \
  __builtin_amdgcn_sched_barrier(0);                                         \
  float _f0 = fmaf(P##0, L2E, -shift),  _f1 = fmaf(P##1, L2E, -shift);       \
  float _f2 = fmaf(P##2, L2E, -shift),  _f3 = fmaf(P##3, L2E, -shift);       \
  float _f4 = fmaf(P##4, L2E, -shift),  _f5 = fmaf(P##5, L2E, -shift);       \
  float _f6 = fmaf(P##6, L2E, -shift),  _f7 = fmaf(P##7, L2E, -shift);       \
  float _f8 = fmaf(P##8, L2E, -shift),  _f9 = fmaf(P##9, L2E, -shift);       \
  float _f10 = fmaf(P##10, L2E, -shift), _f11 = fmaf(P##11, L2E, -shift);    \
  LOAD12(P); /* refill this slot for t+4 (anti-dep keeps it after the fmas)*/\
  float _y0 = _c0.x + _f0,  _y1 = _c0.y + _f1;                               \
  float _y2 = _c0.z + _f2,  _y3 = _c0.w + _f3;                               \
  float _y4 = _c1.x + _f4,  _y5 = _c1.y + _f5;                               \
  float _y6 = _c1.z + _f6,  _y7 = _c1.w + _f7;                               \
  float _y8 = _c2.x + _f8,  _y9 = _c2.y + _f9;                               \
  float _y10 = _c2.z + _f10, _y11 = _c2.w + _f11;                            \
  float _eA = (fast_exp2(_y0) + fast_exp2(_y1)) +                            \
              (fast_exp2(_y2) + fast_exp2(_y3));                             \
  float _eB = (fast_exp2(_y4) + fast_exp2(_y5)) +                            \
              (fast_exp2(_y6) + fast_exp2(_y7));                             \
  float _eC = (fast_exp2(_y8) + fast_exp2(_y9)) +                            \
              (fast_exp2(_y10) + fast_exp2(_y11));                           \
  float _ss = _eA + _eB + _eC;                                               \
  _ss += dppf<0xB1>(_ss);                                                    \
  _ss += dppf<0x4E>(_ss);                                                    \
  float _mA = fmaxf(fmaxf(_y0, _y1), fmaxf(_y2, _y3));                       \
  float _mB = fmaxf(fmaxf(_y4, _y5), fmaxf(_y6, _y7));                       \
  float _mC = fmaxf(fmaxf(_y8, _y9), fmaxf(_y10, _y11));                     \
  float _mm = fmaxf(fmaxf(_mA, _mB), _mC);                                   \
  _mm = fmaxf(_mm, dppf<0xB1>(_mm));                                         \
  _mm = fmaxf(_mm, dppf<0x4E>(_mm));                                         \
  float _cn = shift + fast_log2(_ss);                                        \
  shift = shift + _mm; /* next step's shift (quad-uniform) */                \
  if (ig == 0) carry_g[_wr][j] = _cn;                                        \
  asm volatile("s_waitcnt lgkmcnt(0)" ::: "memory");                         \
  __builtin_amdgcn_s_barrier();                                              \
} while (0)

__global__ __launch_bounds__(192, 1) void crf_kernel(
    const float* __restrict__ feat,
    const int* __restrict__ targets,
    const int* __restrict__ lengths,
    float* __restrict__ ws,      // ws[0]=float accum, ws[1]=int counter (memset 0)
    float* __restrict__ out) {

  __shared__ float carry_g[2][KK];
  __shared__ float red[4];

  const int b   = blockIdx.x;
  const int len = lengths[b];
  const int tid = threadIdx.x;
  const int w   = tid >> 6;
  const int l   = tid & 63;
  const int j0  = l >> 2;
  const int ig  = l & 3;
  const int j   = w * 16 + j0;
  const float* fb = feat + (size_t)b * TT * KK2;

  // ---------- gold partial (one-time scattered gathers, drained at barrier) ----------
  float gsum = 0.f;
  for (int t = tid; t < TT; t += 192)
    if (t < len) gsum += fb[(size_t)t * KK2 + targets[b * TT + t]];
  #pragma unroll
  for (int mk = 1; mk < 64; mk <<= 1) gsum += __shfl_xor(gsum, mk, 64);
  if (l == 0) red[w] = gsum;

  // ---------- carry init (log2 domain, natural layout) + initial shift ----------
  if (tid < KK) carry_g[0][tid] = fb[START_TAG * KK + tid] * L2E;
  float shift = fb[START_TAG * KK + j] * L2E;   // quad-uniform (depends on j only)

  __syncthreads();   // full drain: all pre-loop VMEM/LDS complete; vmcnt score = 0
  const float gold_b = red[0] + red[1] + red[2];

  // ---------- SRSRC buffer descriptor (uniform -> SGPR quad) ----------
  union { const float* p; unsigned int u[2]; } ba; ba.p = fb;
  v4i rsrc;
  rsrc.x = (int)ba.u[0];
  rsrc.y = (int)(ba.u[1] & 0xFFFFu);                 // base hi16, stride=0
  rsrc.z = (int)((unsigned)(BB - b) * TT * KK2 * 4); // bytes to end: OOB reads -> 0
  rsrc.w = 0x00020000;                               // raw dword access

  // per-thread voffset for t=1: t*9216 + (ig*12)*192 + j*4
  unsigned int voff = (unsigned)(KK2 * 4) + (unsigned)(ig * 12 * KK * 4)
                    + (unsigned)(j * 4);

  // ---------- prologue: fill the 4-slot ring (t = 1..4) ----------
  float pa0,pa1,pa2,pa3,pa4,pa5,pa6,pa7,pa8,pa9,pa10,pa11;
  float pb0,pb1,pb2,pb3,pb4,pb5,pb6,pb7,pb8,pb9,pb10,pb11;
  float pc0,pc1,pc2,pc3,pc4,pc5,pc6,pc7,pc8,pc9,pc10,pc11;
  float pd0,pd1,pd2,pd3,pd4,pd5,pd6,pd7,pd8,pd9,pd10,pd11;
  LOAD12(pa); LOAD12(pb); LOAD12(pc); LOAD12(pd);

  // ---------- main scan: unrolled x4, slot sigma = (t-1)&3 ----------
  for (int tb = 1; tb < len; tb += 4) {
    { STEP(pa, tb); }
    if (tb + 1 < len) { STEP(pb, tb + 1); }
    if (tb + 2 < len) { STEP(pc, tb + 2); }
    if (tb + 3 < len) { STEP(pd, tb + 3); }
  }
  asm volatile("s_waitcnt vmcnt(0)" ::: "memory");   // drain leftover prefetches

  // ---------- epilogue ----------
  if (tid == 0) {
    const int rdf = (len - 1) & 1;    // len==1 -> init buffer
    float v = carry_g[rdf][STOP_TAG] * LN2 - gold_b;
    atomicAdd(&ws[0], v);
    __threadfence();
    int done = atomicAdd((int*)&ws[1], 1);
    if (done == BB - 1) out[0] = atomicAdd(&ws[0], 0.0f) / (float)BB;
  }
}

extern "C" void kernel_launch(void* const* d_in, const int* in_sizes, int n_in,
                              void* d_out, int out_size, void* d_ws, size_t ws_size,
                              hipStream_t stream) {
  const float* feat  = (const float*)d_in[0];
  const int* targets = (const int*)d_in[1];
  const int* lengths = (const int*)d_in[2];
  float* ws  = (float*)d_ws;
  float* out = (float*)d_out;

  hipMemsetAsync(d_ws, 0, 16, stream);   // zero accum + counter
  crf_kernel<<<BB, 192, 0, stream>>>(feat, targets, lengths, ws, out);
}

// Round 8
// 383.497 us; speedup vs baseline: 1.6671x; 1.0163x over previous
//
#include <hip/hip_runtime.h>

#define BB 32
#define TT 512
#define KK 48
#define KK2 2304          // 48*48
#define START_TAG 46
#define STOP_TAG 47
#define L2E 1.4426950408889634f
#define LN2 0.6931471805599453f

typedef int v4i __attribute__((ext_vector_type(4)));

__device__ inline float fast_exp2(float x) {
#if __has_builtin(__builtin_amdgcn_exp2f)
  return __builtin_amdgcn_exp2f(x);
#else
  return exp2f(x);
#endif
}
__device__ inline float fast_log2(float x) {
#if __has_builtin(__builtin_amdgcn_logf)
  return __builtin_amdgcn_logf(x);
#else
  return log2f(x);
#endif
}

// quad_perm DPP: 0xB1 = swap lane^1, 0x4E = swap lane^2 (within each quad)
template <int CTRL>
__device__ inline float dppf(float v) {
  int i = __float_as_int(v);
  int r = __builtin_amdgcn_update_dpp(i, i, CTRL, 0xF, 0xF, false);
  return __int_as_float(r);
}

// One block per batch. 192 threads = 3 waves.
// lane l: j0=l>>2 (0..15), ig=l&3; column j=16w+j0; rows i = ig*12 + r.
// LINEAR-SPACE recurrence: state u[i] = 2^(carry[i] - M). Per step:
//   v[j] = sum_i 2^(feat[i][j]*log2e) * u[i]   (pure fma chain on the recurrence)
//   u'[j] = v[j] * 2^(127 - ebits(u[40]));  M += ebits(u[40]) - 127   (uniform)
// The 12 exps per lane act only on prefetched features -> OFF the chain,
// hidden under the carry ds_read latency. No max/log/sub on the chain.
// Features: inline-asm buffer_load ring, depth 4, counted vmcnt(36).
// Carry u: LDS, double-buffered, natural layout; 3x broadcast ds_read_b128
// + 1 broadcast b32 (ref) + 1 ds_write per step + lgkmcnt(0) + raw s_barrier.

#define BL(dst, OFFLIT)                                                      \
  asm volatile("buffer_load_dword %0, %1, %2, 0 offen offset:" OFFLIT        \
               : "=v"(dst) : "v"(voff), "s"(rsrc))
#define LOAD12(P) do {                                                       \
  BL(P##0, "0");    BL(P##1, "192");  BL(P##2, "384");  BL(P##3, "576");     \
  BL(P##4, "768");  BL(P##5, "960");  BL(P##6, "1152"); BL(P##7, "1344");    \
  BL(P##8, "1536"); BL(P##9, "1728"); BL(P##10, "1920"); BL(P##11, "2112");  \
  voff += (unsigned)(KK2 * 4);                                               \
} while (0)

#define STEP(P, TCUR) do {                                                   \
  const int _rd = ((TCUR) - 1) & 1, _wr = (TCUR) & 1;                        \
  float _uref = carry_g[_rd][40];                                            \
  float4 _c0 = *(const float4*)&carry_g[_rd][ig * 12 + 0];                   \
  float4 _c1 = *(const float4*)&carry_g[_rd][ig * 12 + 4];                   \
  float4 _c2 = *(const float4*)&carry_g[_rd][ig * 12 + 8];                   \
  asm volatile("s_waitcnt vmcnt(36)" ::: "memory");                          \
  __builtin_amdgcn_sched_barrier(0);                                         \
  /* off-chain: E = 2^(feat*log2e) on 4-step-old prefetched data */          \
  float _e0 = fast_exp2(P##0 * L2E),  _e1 = fast_exp2(P##1 * L2E);           \
  float _e2 = fast_exp2(P##2 * L2E),  _e3 = fast_exp2(P##3 * L2E);           \
  float _e4 = fast_exp2(P##4 * L2E),  _e5 = fast_exp2(P##5 * L2E);           \
  float _e6 = fast_exp2(P##6 * L2E),  _e7 = fast_exp2(P##7 * L2E);           \
  float _e8 = fast_exp2(P##8 * L2E),  _e9 = fast_exp2(P##9 * L2E);           \
  float _e10 = fast_exp2(P##10 * L2E), _e11 = fast_exp2(P##11 * L2E);        \
  LOAD12(P); /* refill this slot for t+4 */                                  \
  unsigned _eb = (__float_as_uint(_uref) >> 23) & 0xFFu;                     \
  _eb = _eb < 64u ? 64u : (_eb > 190u ? 190u : _eb);  /* safety clamp */     \
  float _scale = __uint_as_float((254u - _eb) << 23);                        \
  Mi += (int)_eb - 127;                                                      \
  /* on-chain: 4 fma chains of depth 3, then tree + quad DPP reduce */       \
  float _h0 = fmaf(_c0.z, _e2, fmaf(_c0.y, _e1, _c0.x * _e0));               \
  float _h1 = fmaf(_c1.y, _e5, fmaf(_c1.x, _e4, _c0.w * _e3));               \
  float _h2 = fmaf(_c2.x, _e8, fmaf(_c1.w, _e7, _c1.z * _e6));               \
  float _h3 = fmaf(_c2.w, _e11, fmaf(_c2.z, _e10, _c2.y * _e9));             \
  float _v = (_h0 + _h1) + (_h2 + _h3);                                      \
  _v += dppf<0xB1>(_v);                                                      \
  _v += dppf<0x4E>(_v);                                                      \
  if (ig == 0) carry_g[_wr][j] = _v * _scale;                                \
  asm volatile("s_waitcnt lgkmcnt(0)" ::: "memory");                         \
  __builtin_amdgcn_s_barrier();                                              \
} while (0)

__global__ __launch_bounds__(192, 1) void crf_kernel(
    const float* __restrict__ feat,
    const int* __restrict__ targets,
    const int* __restrict__ lengths,
    float* __restrict__ ws,      // ws[0]=float accum, ws[1]=int counter (memset 0)
    float* __restrict__ out) {

  __shared__ float carry_g[2][KK];
  __shared__ float red[4];

  const int b   = blockIdx.x;
  const int len = lengths[b];
  const int tid = threadIdx.x;
  const int w   = tid >> 6;
  const int l   = tid & 63;
  const int j0  = l >> 2;
  const int ig  = l & 3;
  const int j   = w * 16 + j0;
  const float* fb = feat + (size_t)b * TT * KK2;

  // ---------- gold partial (one-time scattered gathers) ----------
  float gsum = 0.f;
  for (int t = tid; t < TT; t += 192)
    if (t < len) gsum += fb[(size_t)t * KK2 + targets[b * TT + t]];
  #pragma unroll
  for (int mk = 1; mk < 64; mk <<= 1) gsum += __shfl_xor(gsum, mk, 64);
  if (l == 0) red[w] = gsum;

  // ---------- state init: u[i] = 2^(feat[0,START,i]*log2e), M = 0 ----------
  if (tid < KK) carry_g[0][tid] = fast_exp2(fb[START_TAG * KK + tid] * L2E);
  int Mi = 0;

  __syncthreads();   // full drain; vmcnt score = 0 at loop entry
  const float gold_b = red[0] + red[1] + red[2];

  // ---------- SRSRC buffer descriptor ----------
  union { const float* p; unsigned int u[2]; } ba; ba.p = fb;
  v4i rsrc;
  rsrc.x = (int)ba.u[0];
  rsrc.y = (int)(ba.u[1] & 0xFFFFu);                 // base hi16, stride=0
  rsrc.z = (int)((unsigned)(BB - b) * TT * KK2 * 4); // bytes to end; OOB -> 0
  rsrc.w = 0x00020000;                               // raw dword access

  // per-thread voffset for t=1
  unsigned int voff = (unsigned)(KK2 * 4) + (unsigned)(ig * 12 * KK * 4)
                    + (unsigned)(j * 4);

  // ---------- prologue: fill the 4-slot ring (t = 1..4) ----------
  float pa0,pa1,pa2,pa3,pa4,pa5,pa6,pa7,pa8,pa9,pa10,pa11;
  float pb0,pb1,pb2,pb3,pb4,pb5,pb6,pb7,pb8,pb9,pb10,pb11;
  float pc0,pc1,pc2,pc3,pc4,pc5,pc6,pc7,pc8,pc9,pc10,pc11;
  float pd0,pd1,pd2,pd3,pd4,pd5,pd6,pd7,pd8,pd9,pd10,pd11;
  LOAD12(pa); LOAD12(pb); LOAD12(pc); LOAD12(pd);

  // ---------- main scan: unrolled x4 ----------
  for (int tb = 1; tb < len; tb += 4) {
    { STEP(pa, tb); }
    if (tb + 1 < len) { STEP(pb, tb + 1); }
    if (tb + 2 < len) { STEP(pc, tb + 2); }
    if (tb + 3 < len) { STEP(pd, tb + 3); }
  }
  asm volatile("s_waitcnt vmcnt(0)" ::: "memory");   // drain leftover prefetches

  // ---------- epilogue ----------
  if (tid == 0) {
    const int rdf = (len - 1) & 1;    // len==1 -> init buffer
    float v = (fast_log2(carry_g[rdf][STOP_TAG]) + (float)Mi) * LN2 - gold_b;
    atomicAdd(&ws[0], v);
    __threadfence();
    int done = atomicAdd((int*)&ws[1], 1);
    if (done == BB - 1) out[0] = atomicAdd(&ws[0], 0.0f) / (float)BB;
  }
}

extern "C" void kernel_launch(void* const* d_in, const int* in_sizes, int n_in,
                              void* d_out, int out_size, void* d_ws, size_t ws_size,
                              hipStream_t stream) {
  const float* feat  = (const float*)d_in[0];
  const int* targets = (const int*)d_in[1];
  const int* lengths = (const int*)d_in[2];
  float* ws  = (float*)d_ws;
  float* out = (float*)d_out;

  hipMemsetAsync(d_ws, 0, 16, stream);   // zero accum + counter
  crf_kernel<<<BB, 192, 0, stream>>>(feat, targets, lengths, ws, out);
}